// Round 6
// baseline (418.182 us; speedup 1.0000x reference)
//
#include <hip/hip_runtime.h>
#include <hip/hip_bf16.h>
#include <cstdint>

#define B_  4
#define S_  2048
#define D_  2048
#define H_  16
#define DK_ 128

typedef __attribute__((ext_vector_type(8))) short short8;
typedef __attribute__((ext_vector_type(4))) short s16x4;
typedef __attribute__((ext_vector_type(4))) float f32x4;
typedef unsigned short ushort_t;

__device__ __forceinline__ void gl_lds16(const void* g, void* l) {
  __builtin_amdgcn_global_load_lds(
      (const __attribute__((address_space(1))) uint32_t*)g,
      (__attribute__((address_space(3))) uint32_t*)l, 16, 0, 0);
}

__device__ __forceinline__ ushort_t f2bf(float f) {
  __hip_bfloat16 h = __float2bfloat16(f);
  return *(ushort_t*)&h;
}

// ---------------------------------------------------------------------------
// fused fp32 -> bf16 conversion for x + 4 weight matrices (one launch).
// ---------------------------------------------------------------------------
__global__ __launch_bounds__(256) void cvt_all(
    const float* __restrict__ x,  const float* __restrict__ w0,
    const float* __restrict__ w1, const float* __restrict__ w2,
    const float* __restrict__ w3, ushort_t* __restrict__ dst)
{
  constexpr size_t NE = (size_t)B_ * S_ * D_;
  constexpr size_t NW = (size_t)D_ * D_;
  constexpr int XB = (int)(NE / 8 / 256);
  constexpr int WB = (int)(NW / 8 / 256);

  const int blk = blockIdx.x;
  const float* src;
  size_t base;
  int li;
  if (blk < XB)           { src = x;  base = 0;           li = blk * 256 + threadIdx.x; }
  else if (blk < XB+WB)   { src = w0; base = NE/8;        li = (blk-XB)     * 256 + threadIdx.x; }
  else if (blk < XB+2*WB) { src = w1; base = (NE+NW)/8;   li = (blk-XB-WB)  * 256 + threadIdx.x; }
  else if (blk < XB+3*WB) { src = w2; base = (NE+2*NW)/8; li = (blk-XB-2*WB)* 256 + threadIdx.x; }
  else                    { src = w3; base = (NE+3*NW)/8; li = (blk-XB-3*WB)* 256 + threadIdx.x; }

  float4 a = ((const float4*)src)[li * 2];
  float4 b = ((const float4*)src)[li * 2 + 1];
  short8 o;
  o[0] = (short)f2bf(a.x); o[1] = (short)f2bf(a.y);
  o[2] = (short)f2bf(a.z); o[3] = (short)f2bf(a.w);
  o[4] = (short)f2bf(b.x); o[5] = (short)f2bf(b.y);
  o[6] = (short)f2bf(b.z); o[7] = (short)f2bf(b.w);
  ((short8*)dst)[base + li] = o;
}

// ---------------------------------------------------------------------------
// 256x256 / BK=64 / 8-wave / 4-phase GEMM — EXACT round-0 body (verified
// 215 us / MfmaUtil 40.6%; 196 us with r20 epilogue).  Single 64KB LDS
// buffer, phase-granular region recycling:
//   region death: A(q0),B(q0) after phA reads; B(q1) after phB; A(q1) after phC
//   stage tile t+1: {A(q0),B(q0)}@phB, B(q1)@phC, A(q1)@phD
//   waits (loads): phA-end vmcnt(2); phB-end vmcnt(4)|0; phD-end vmcnt(4)|0
// r17/r18 (8-phase dbuf) and r19 (merged phases) all regressed -> this body
// is the local optimum at 2 waves/SIMD.  DO NOT restructure the loop.
// r21 (proj fastest-varying) regressed: per-XCD L2 working set tripled (3 W
// matrices resident), FETCH 148->330MB.  Keep proj OUTERMOST (r13 ordering).
// ---------------------------------------------------------------------------
#define STAGE_A(q, tt) do {                                                \
    int r0_ = (q) * 64 + w * 8;                                            \
    gl_lds16(Agb + (size_t)(r0_ + lr) * 2048 + (tt) * 64 + lc, &As[r0_ * 64]); \
    r0_ += 128;                                                            \
    gl_lds16(Agb + (size_t)(r0_ + lr) * 2048 + (tt) * 64 + lc, &As[r0_ * 64]); \
  } while (0)
#define STAGE_B(q, tt) do {                                                \
    int r0_ = (w >> 1) * 64 + (q) * 32 + ((w & 1) * 2) * 8;                \
    gl_lds16(Wgb + (size_t)(r0_ + lr) * 2048 + (tt) * 64 + lc, &Bs[r0_ * 64]); \
    r0_ += 8;                                                              \
    gl_lds16(Wgb + (size_t)(r0_ + lr) * 2048 + (tt) * 64 + lc, &Bs[r0_ * 64]); \
  } while (0)

#define GEMM_BODY()                                                               \
  f32x4 acc[8][4] = {};                                                           \
  short8 aA[4][2];                                                                \
  short8 bB[2][2][2];                                                             \
  STAGE_A(0, 0); STAGE_A(1, 0); STAGE_B(0, 0); STAGE_B(1, 0);                     \
  asm volatile("s_waitcnt vmcnt(0)" ::: "memory");                                \
  __builtin_amdgcn_s_barrier();                                                   \
  for (int kt = 0; kt < NT; ++kt) {                                               \
    /* phase A : read A(q0), B(q0); compute quadrant (qm0,qn0) */                 \
    _Pragma("unroll")                                                             \
    for (int fm = 0; fm < 4; ++fm)                                                \
      _Pragma("unroll")                                                           \
      for (int kk = 0; kk < 2; ++kk) {                                            \
        const int row = wm * 128 + fm * 16 + l15;                                 \
        aA[fm][kk] = *(const short8*)&As[row * 64 + (((kk * 4 + lhi) ^ (l15 & 7)) << 3)]; \
      }                                                                           \
    _Pragma("unroll")                                                             \
    for (int fn = 0; fn < 2; ++fn)                                                \
      _Pragma("unroll")                                                           \
      for (int kk = 0; kk < 2; ++kk) {                                            \
        const int row = wn * 64 + fn * 16 + l15;                                  \
        bB[0][fn][kk] = *(const short8*)&Bs[row * 64 + (((kk * 4 + lhi) ^ (l15 & 7)) << 3)]; \
      }                                                                           \
    __builtin_amdgcn_s_barrier();                                                 \
    __builtin_amdgcn_s_setprio(1);                                                \
    _Pragma("unroll")                                                             \
    for (int kk = 0; kk < 2; ++kk)                                                \
      _Pragma("unroll")                                                           \
      for (int fm = 0; fm < 4; ++fm)                                              \
        _Pragma("unroll")                                                         \
        for (int fn = 0; fn < 2; ++fn)                                            \
          acc[fm][fn] = __builtin_amdgcn_mfma_f32_16x16x32_bf16(aA[fm][kk], bB[0][fn][kk], acc[fm][fn], 0, 0, 0); \
    __builtin_amdgcn_s_setprio(0);                                                \
    asm volatile("s_waitcnt vmcnt(2)" ::: "memory");  /* force B(t,q1) */         \
    __builtin_amdgcn_s_barrier();                                                 \
    /* phase B : read B(q1); stage A(t+1,q0)+B(t+1,q0); quadrant (qm0,qn1) */     \
    _Pragma("unroll")                                                             \
    for (int fn = 0; fn < 2; ++fn)                                                \
      _Pragma("unroll")                                                           \
      for (int kk = 0; kk < 2; ++kk) {                                            \
        const int row = wn * 64 + 32 + fn * 16 + l15;                             \
        bB[1][fn][kk] = *(const short8*)&Bs[row * 64 + (((kk * 4 + lhi) ^ (l15 & 7)) << 3)]; \
      }                                                                           \
    if (kt + 1 < NT) { STAGE_A(0, kt + 1); STAGE_B(0, kt + 1); }                  \
    __builtin_amdgcn_s_barrier();                                                 \
    __builtin_amdgcn_s_setprio(1);                                                \
    _Pragma("unroll")                                                             \
    for (int kk = 0; kk < 2; ++kk)                                                \
      _Pragma("unroll")                                                           \
      for (int fm = 0; fm < 4; ++fm)                                              \
        _Pragma("unroll")                                                         \
        for (int fn = 0; fn < 2; ++fn)                                            \
          acc[fm][2 + fn] = __builtin_amdgcn_mfma_f32_16x16x32_bf16(aA[fm][kk], bB[1][fn][kk], acc[fm][2 + fn], 0, 0, 0); \
    __builtin_amdgcn_s_setprio(0);                                                \
    if (kt + 1 < NT) { asm volatile("s_waitcnt vmcnt(4)" ::: "memory"); }         \
    else             { asm volatile("s_waitcnt vmcnt(0)" ::: "memory"); }         \
    __builtin_amdgcn_s_barrier();      /* A(t,q1) now forced */                   \
    /* phase C : read A(q1); stage B(t+1,q1); quadrant (qm1,qn0) */               \
    _Pragma("unroll")                                                             \
    for (int fm = 0; fm < 4; ++fm)                                                \
      _Pragma("unroll")                                                           \
      for (int kk = 0; kk < 2; ++kk) {                                            \
        const int row = wm * 128 + 64 + fm * 16 + l15;                            \
        aA[fm][kk] = *(const short8*)&As[row * 64 + (((kk * 4 + lhi) ^ (l15 & 7)) << 3)]; \
      }                                                                           \
    if (kt + 1 < NT) STAGE_B(1, kt + 1);                                          \
    __builtin_amdgcn_s_barrier();                                                 \
    __builtin_amdgcn_s_setprio(1);                                                \
    _Pragma("unroll")                                                             \
    for (int kk = 0; kk < 2; ++kk)                                                \
      _Pragma("unroll")                                                           \
      for (int fm = 0; fm < 4; ++fm)                                              \
        _Pragma("unroll")                                                         \
        for (int fn = 0; fn < 2; ++fn)                                            \
          acc[4 + fm][fn] = __builtin_amdgcn_mfma_f32_16x16x32_bf16(aA[fm][kk], bB[0][fn][kk], acc[4 + fm][fn], 0, 0, 0); \
    __builtin_amdgcn_s_setprio(0);                                                \
    __builtin_amdgcn_s_barrier();                                                 \
    /* phase D : stage A(t+1,q1); quadrant (qm1,qn1) */                           \
    if (kt + 1 < NT) STAGE_A(1, kt + 1);                                          \
    __builtin_amdgcn_s_setprio(1);                                                \
    _Pragma("unroll")                                                             \
    for (int kk = 0; kk < 2; ++kk)                                                \
      _Pragma("unroll")                                                           \
      for (int fm = 0; fm < 4; ++fm)                                              \
        _Pragma("unroll")                                                         \
        for (int fn = 0; fn < 2; ++fn)                                            \
          acc[4 + fm][2 + fn] = __builtin_amdgcn_mfma_f32_16x16x32_bf16(aA[fm][kk], bB[1][fn][kk], acc[4 + fm][2 + fn], 0, 0, 0); \
    __builtin_amdgcn_s_setprio(0);                                                \
    if (kt + 1 < NT) { asm volatile("s_waitcnt vmcnt(4)" ::: "memory"); }         \
    else             { asm volatile("s_waitcnt vmcnt(0)" ::: "memory"); }         \
    __builtin_amdgcn_s_barrier();      /* A/B(t+1,q0) now forced */               \
  }

// ---------------------------------------------------------------------------
// Fused QKV projection GEMM. Grid 768 (r13 L2-aware swizzle, proj OUTERMOST).
// r20: Q/K epilogue routed through LDS transpose (As dead post-loop) ->
// dk-contiguous short8 stores (WRITE_SIZE 180->104MB).  V path unchanged.
// ---------------------------------------------------------------------------
__global__ __launch_bounds__(512, 2) void gemmQKV(
    const ushort_t* __restrict__ A,
    const ushort_t* __restrict__ Wqm, const ushort_t* __restrict__ Wkm,
    const ushort_t* __restrict__ Wvm,
    const float* __restrict__ bq, const float* __restrict__ bk,
    const float* __restrict__ bv,
    ushort_t* __restrict__ Qo, ushort_t* __restrict__ Ko,
    ushort_t* __restrict__ Vo)
{
  constexpr int NT = D_ / 64;

  __shared__ ushort_t As[256 * 64];
  __shared__ ushort_t Bs[256 * 64];

  const int bid = blockIdx.x;
  const int c = bid & 7;
  const int j0 = bid >> 3;                // 0..95
  const int proj = j0 >> 5;               // 0..2  (outermost — r21 revert)
  const int s = j0 & 31;
  const int tnl = s & 7;
  const int tm = c * 4 + (s >> 3);

  const ushort_t* Wsel = (proj == 0) ? Wqm : (proj == 1) ? Wkm : Wvm;
  const float*    bsel = (proj == 0) ? bq  : (proj == 1) ? bk  : bv;
  ushort_t*       osel = (proj == 0) ? Qo  : (proj == 1) ? Ko  : Vo;

  const int t = threadIdx.x;
  const int l = t & 63;
  const int w = t >> 6;
  const int wm = w >> 2;
  const int wn = w & 3;
  const int l15 = l & 15, lhi = l >> 4;
  const int lr = l >> 3;
  const int lc = ((l & 7) ^ lr) * 8;

  const ushort_t* Agb = A + (size_t)(tm * 256) * 2048;
  const ushort_t* Wgb = Wsel + (size_t)(tnl * 256) * 2048;

  GEMM_BODY()

  if (proj == 2) {
    // V: store V^T (b,h,dk,s) — s16x4 packs give dense 128B coverage already.
#pragma unroll
    for (int qn = 0; qn < 2; ++qn)
#pragma unroll
      for (int fn = 0; fn < 2; ++fn) {
        const int e = tnl * 256 + wn * 64 + qn * 32 + fn * 16 + l15;
        const float bvv = bsel[e];
        const int h = e >> 7, dk = e & (DK_ - 1);
#pragma unroll
        for (int qm = 0; qm < 2; ++qm)
#pragma unroll
          for (int fm = 0; fm < 4; ++fm) {
            const int srow0 = tm * 256 + wm * 128 + qm * 64 + fm * 16 + lhi * 4;
            const f32x4 v4 = acc[qm * 4 + fm][qn * 2 + fn];
            const int b = srow0 >> 11, s0 = srow0 & (S_ - 1);
            s16x4 pk;
#pragma unroll
            for (int r = 0; r < 4; ++r) pk[r] = (short)f2bf(v4[r] + bvv);
            *(s16x4*)(osel + (((size_t)b * H_ + h) * DK_ + dk) * S_ + s0) = pk;
          }
      }
  } else {
    // Q/K: per (qm,qn) 128x128 chunk, acc -> LDS (bank-swizzled) -> short8
    // dk-contiguous stores.
#pragma unroll
    for (int qm = 0; qm < 2; ++qm)
#pragma unroll
      for (int qn = 0; qn < 2; ++qn) {
        __syncthreads();   // previous chunk fully read (no-op cost 1st iter)
#pragma unroll
        for (int fn = 0; fn < 2; ++fn) {
          const int e = tnl * 256 + wn * 64 + qn * 32 + fn * 16 + l15;
          const float bvv = bsel[e];
          const int lcol = wn * 32 + fn * 16 + l15;
#pragma unroll
          for (int fm = 0; fm < 4; ++fm) {
            const f32x4 v4 = acc[qm * 4 + fm][qn * 2 + fn];
#pragma unroll
            for (int r = 0; r < 4; ++r) {
              const int lrow = wm * 64 + fm * 16 + lhi * 4 + r;
              As[lrow * 128 + (lcol ^ ((lrow & 7) << 3))] = f2bf(v4[r] + bvv);
            }
          }
        }
        __syncthreads();   // writes visible
        {
          const int erow = t >> 2;          // 0..127 chunk-local row
          const int eli  = t & 3;           // 8-dk segment within 32-col block
          const int grow = tm * 256 + (erow >> 6) * 128 + qm * 64 + (erow & 63);
          const int bb = grow >> 11, sR = grow & (S_ - 1);
#pragma unroll
          for (int wnb = 0; wnb < 4; ++wnb) {
            const int lcol = wnb * 32 + eli * 8;
            short8 v = *(const short8*)&As[erow * 128 + (lcol ^ ((erow & 7) << 3))];
            const int col = wnb * 64 + qn * 32 + eli * 8;
            const int e2 = tnl * 256 + col;
            const int h = e2 >> 7, dk = e2 & (DK_ - 1);
            *(short8*)(osel + (((size_t)bb * H_ + h) * S_ + sR) * DK_ + dk) = v;
          }
        }
      }
  }
}

// ---------------------------------------------------------------------------
// Output projection GEMM: fp32 MxN. grid 256.  (fp32 stores are already
// 64B-dense per 16-lane group — no epilogue change.)
// ---------------------------------------------------------------------------
__global__ __launch_bounds__(512, 2) void gemmOut(
    const ushort_t* __restrict__ A,
    const ushort_t* __restrict__ W,
    const float* __restrict__ bias,
    float* __restrict__ outp)
{
  constexpr int NT = D_ / 64;
  constexpr int NWG = (B_ * S_ / 256) * (D_ / 256);

  __shared__ ushort_t As[256 * 64];
  __shared__ ushort_t Bs[256 * 64];

  const int bid = blockIdx.x;
  const int swz = (bid & 7) * (NWG / 8) + (bid >> 3);
  const int tm = swz >> 3;
  const int tn = swz & 7;

  const int t = threadIdx.x;
  const int l = t & 63;
  const int w = t >> 6;
  const int wm = w >> 2;
  const int wn = w & 3;
  const int l15 = l & 15, lhi = l >> 4;
  const int lr = l >> 3;
  const int lc = ((l & 7) ^ lr) * 8;

  const ushort_t* Agb = A + (size_t)(tm * 256) * 2048;
  const ushort_t* Wgb = W + (size_t)(tn * 256) * 2048;

  GEMM_BODY()

#pragma unroll
  for (int qn = 0; qn < 2; ++qn)
#pragma unroll
    for (int fn = 0; fn < 2; ++fn) {
      const int e = tn * 256 + wn * 64 + qn * 32 + fn * 16 + l15;
      const float bvv = bias[e];
#pragma unroll
      for (int qm = 0; qm < 2; ++qm)
#pragma unroll
        for (int fm = 0; fm < 4; ++fm) {
          const int srow0 = tm * 256 + wm * 128 + qm * 64 + fm * 16 + lhi * 4;
          const f32x4 v4 = acc[qm * 4 + fm][qn * 2 + fn];
#pragma unroll
          for (int r = 0; r < 4; ++r)
            outp[(size_t)(srow0 + r) * D_ + e] = v4[r] + bvv;
        }
    }
}
#undef STAGE_A
#undef STAGE_B
#undef GEMM_BODY

// ---------------------------------------------------------------------------
// Causal flash attention — r10 main loop unchanged.
// r22: C-write epilogue routed through warp-private Pl[w] LDS (dead at
// epilogue) in two 64-dk halves: acc -> LDS (XOR-swizzled) -> short8
// dk-contiguous stores (4 lanes fill a full 64B line).  Replaces 64 scalar
// 2B stores/thread (half-line fill, ~2x write amp like pre-r20 Q/K).
// Warp-private buffer => no new barriers.
// ---------------------------------------------------------------------------
__global__ __launch_bounds__(256, 2) void attn_kern(
    const ushort_t* __restrict__ Q,
    const ushort_t* __restrict__ K,
    const ushort_t* __restrict__ Vt,
    ushort_t* __restrict__ C)
{
  __shared__ ushort_t Ks[2][64 * 128];
  __shared__ ushort_t Vs[2][128 * 64];
  __shared__ ushort_t Pl[4][32 * 64];

  const int bid = blockIdx.x;
  const int i = bid >> 3;
  const int bh = (bid & 7) * 8 + (i >> 3);
  const int qp = i & 7;

  const ushort_t* Qg = Q + (size_t)bh * S_ * DK_;
  const ushort_t* Kg = K + (size_t)bh * S_ * DK_;
  const ushort_t* Vg = Vt + (size_t)bh * DK_ * S_;
  const int b = bh >> 4, h = bh & 15;

  const int t = threadIdx.x;
  const int l = t & 63;
  const int w = t >> 6;
  const int l15 = l & 15, lhi = l >> 4;

  const float cs = 0.08838834764831845f * 1.4426950408889634f;
  const float DEFER_RAW = 8.0f / cs;

  short8 ones;
#pragma unroll
  for (int j = 0; j < 8; ++j) ones[j] = (short)0x3F80;

  int koff[4], voff[4];
#pragma unroll
  for (int j = 0; j < 4; ++j) {
    const int krow = w * 16 + j * 4 + lhi;
    koff[j] = krow * DK_ + 8 * (l15 ^ ((j * 4 + lhi) & 7));
    const int vrow = (w * 4 + j) * 8 + (l >> 3);
    voff[j] = vrow * S_ + 8 * ((l & 7) ^ (l >> 3));
  }
  int kcol[4];
#pragma unroll
  for (int kt = 0; kt < 4; ++kt)
    kcol[kt] = ((kt * 64 + lhi * 16) ^ ((l15 & 7) << 4)) >> 1;
  int vcol[2];
#pragma unroll
  for (int hb = 0; hb < 2; ++hb)
    vcol[hb] = ((hb * 64 + lhi * 16) ^ ((l15 & 7) << 4)) >> 1;

#define STAGE_KV(pb, kvv) do {                                              \
    _Pragma("unroll")                                                       \
    for (int j = 0; j < 4; ++j) {                                           \
      gl_lds16(Kg + (size_t)(kvv) * DK_ + koff[j], Ks[pb] + (w * 4 + j) * 512); \
      gl_lds16(Vg + (size_t)(kvv) + voff[j],       Vs[pb] + (w * 4 + j) * 512); \
    }                                                                       \
  } while (0)

  for (int pass = 0; pass < 2; ++pass) {
    const int qb = pass ? (15 - qp) : qp;
    const int qrow0 = qb * 128 + w * 32;
    const int nkv = 2 * (qb + 1);

    short8 qa[2][4];
#pragma unroll
    for (int rf = 0; rf < 2; ++rf)
#pragma unroll
      for (int kt = 0; kt < 4; ++kt)
        qa[rf][kt] = *(const short8*)(Qg + (size_t)(qrow0 + rf * 16 + l15) * DK_ + kt * 32 + lhi * 8);

    f32x4 o[2][8] = {};
    f32x4 lsum[2] = {};
    float mrow[2][4];
#pragma unroll
    for (int rf = 0; rf < 2; ++rf)
#pragma unroll
      for (int r = 0; r < 4; ++r) mrow[rf][r] = -1e30f;

    STAGE_KV(0, 0);
    asm volatile("s_waitcnt vmcnt(0)" ::: "memory");
    __syncthreads();

    for (int kvt = 0; kvt < nkv; ++kvt) {
      const int kv = kvt * 64;
      const int p = kvt & 1;

      if (kvt + 1 < nkv) STAGE_KV(p ^ 1, kv + 64);

      f32x4 sf[2][4] = {};
      __builtin_amdgcn_s_setprio(1);
#pragma unroll
      for (int f = 0; f < 4; ++f) {
#pragma unroll
        for (int kt = 0; kt < 4; ++kt) {
          short8 kb = *(const short8*)(Ks[p] + (f * 16 + l15) * 128 + kcol[kt]);
          sf[0][f] = __builtin_amdgcn_mfma_f32_16x16x32_bf16(qa[0][kt], kb, sf[0][f], 0, 0, 0);
          sf[1][f] = __builtin_amdgcn_mfma_f32_16x16x32_bf16(qa[1][kt], kb, sf[1][f], 0, 0, 0);
        }
      }
      __builtin_amdgcn_s_setprio(0);

      float pmax[2][4];
#pragma unroll
      for (int rf = 0; rf < 2; ++rf)
#pragma unroll
        for (int r = 0; r < 4; ++r) pmax[rf][r] = -1e30f;
      const bool domask = (kv + 63 > qrow0);
      if (domask) {
#pragma unroll
        for (int f = 0; f < 4; ++f) {
          const int col = kv + f * 16 + l15;
#pragma unroll
          for (int rf = 0; rf < 2; ++rf)
#pragma unroll
            for (int r = 0; r < 4; ++r) {
              const int row = qrow0 + rf * 16 + lhi * 4 + r;
              if (col > row) sf[rf][f][r] = -1e30f;
              pmax[rf][r] = fmaxf(pmax[rf][r], sf[rf][f][r]);
            }
        }
      } else {
#pragma unroll
        for (int f = 0; f < 4; ++f)
#pragma unroll
          for (int rf = 0; rf < 2; ++rf)
#pragma unroll
            for (int r = 0; r < 4; ++r)
              pmax[rf][r] = fmaxf(pmax[rf][r], sf[rf][f][r]);
      }
#pragma unroll
      for (int d = 1; d < 16; d <<= 1)
#pragma unroll
        for (int rf = 0; rf < 2; ++rf)
#pragma unroll
          for (int r = 0; r < 4; ++r)
            pmax[rf][r] = fmaxf(pmax[rf][r], __shfl_xor(pmax[rf][r], d, 64));

      bool need = false;
#pragma unroll
      for (int rf = 0; rf < 2; ++rf)
#pragma unroll
        for (int r = 0; r < 4; ++r) need |= (pmax[rf][r] > mrow[rf][r] + DEFER_RAW);
      if (__any(need)) {
#pragma unroll
        for (int rf = 0; rf < 2; ++rf)
#pragma unroll
          for (int r = 0; r < 4; ++r) {
            const float mn = fmaxf(mrow[rf][r], pmax[rf][r]);
            const float alpha = __builtin_amdgcn_exp2f((mrow[rf][r] - mn) * cs);
            mrow[rf][r] = mn;
            lsum[rf][r] *= alpha;
#pragma unroll
            for (int n = 0; n < 8; ++n) o[rf][n][r] *= alpha;
          }
      }

      ushort_t* P = Pl[w];
#pragma unroll
      for (int f = 0; f < 4; ++f)
#pragma unroll
        for (int rf = 0; rf < 2; ++rf)
#pragma unroll
          for (int r = 0; r < 4; ++r) {
            const float pv = __builtin_amdgcn_exp2f((sf[rf][f][r] - mrow[rf][r]) * cs);
            const int prow = rf * 16 + lhi * 4 + r;
            P[prow * 64 + ((f * 16 + l15) ^ ((prow & 7) << 3))] = f2bf(pv);
          }

      asm volatile("s_waitcnt lgkmcnt(0)" ::: "memory");
      short8 pa[2][2];
#pragma unroll
      for (int rf = 0; rf < 2; ++rf)
#pragma unroll
        for (int ks = 0; ks < 2; ++ks) {
          const int prow = rf * 16 + l15;
          pa[rf][ks] = *(const short8*)(P + prow * 64 + ((ks * 32 + lhi * 8) ^ ((prow & 7) << 3)));
        }

      __builtin_amdgcn_s_setprio(1);
#pragma unroll
      for (int rf = 0; rf < 2; ++rf) {
        lsum[rf] = __builtin_amdgcn_mfma_f32_16x16x32_bf16(pa[rf][0], ones, lsum[rf], 0, 0, 0);
        lsum[rf] = __builtin_amdgcn_mfma_f32_16x16x32_bf16(pa[rf][1], ones, lsum[rf], 0, 0, 0);
      }
#pragma unroll
      for (int n = 0; n < 8; ++n) {
#pragma unroll
        for (int hb = 0; hb < 2; ++hb) {
          short8 vb = *(const short8*)(Vs[p] + (n * 16 + l15) * 64 + vcol[hb]);
          o[0][n] = __builtin_amdgcn_mfma_f32_16x16x32_bf16(pa[0][hb], vb, o[0][n], 0, 0, 0);
          o[1][n] = __builtin_amdgcn_mfma_f32_16x16x32_bf16(pa[1][hb], vb, o[1][n], 0, 0, 0);
        }
      }
      __builtin_amdgcn_s_setprio(0);

      asm volatile("s_waitcnt vmcnt(0)" ::: "memory");
      __syncthreads();
    }

    // r22 epilogue: normalize -> warp-private LDS (two 64-dk halves) ->
    // dk-contiguous short8 stores (4 lanes fill a full 64B line).
    {
      float linv2[2][4];
#pragma unroll
      for (int rf = 0; rf < 2; ++rf)
#pragma unroll
        for (int r = 0; r < 4; ++r) linv2[rf][r] = 1.0f / lsum[rf][r];

      ushort_t* T = Pl[w];
#pragma unroll
      for (int hb = 0; hb < 2; ++hb) {
        // write half: local rows 0..31, local cols (dk - hb*64) 0..63
#pragma unroll
        for (int rf = 0; rf < 2; ++rf)
#pragma unroll
          for (int nn = 0; nn < 4; ++nn) {
            const int n = hb * 4 + nn;
#pragma unroll
            for (int r = 0; r < 4; ++r) {
              const int lrow = rf * 16 + lhi * 4 + r;
              const int lcol = nn * 16 + l15;
              const int swg = ((lrow & 7) ^ (lrow >> 3)) & 7;
              T[lrow * 64 + (lcol ^ (swg << 3))] = f2bf(o[rf][n][r] * linv2[rf][r]);
            }
          }
        // read back + store: lane pair (2 lanes/row) covers one 32-row half
        {
          const int row = l >> 1;
          const int swg = ((row & 7) ^ (row >> 3)) & 7;
          const size_t gbase = (((size_t)b * S_ + qrow0 + row) * H_ + h) * DK_ + hb * 64;
#pragma unroll
          for (int g = 0; g < 4; ++g) {
            const int gi = (l & 1) * 4 + g;
            short8 v = *(const short8*)&T[row * 64 + ((gi ^ swg) << 3)];
            *(short8*)(C + gbase + gi * 8) = v;
          }
        }
      }
    }
  }
#undef STAGE_KV
}

// ---------------------------------------------------------------------------
extern "C" void kernel_launch(void* const* d_in, const int* in_sizes, int n_in,
                              void* d_out, int out_size, void* d_ws, size_t ws_size,
                              hipStream_t stream) {
  const float* x  = (const float*)d_in[0];
  const float* Wq = (const float*)d_in[1];
  const float* bq = (const float*)d_in[2];
  const float* Wk = (const float*)d_in[3];
  const float* bk = (const float*)d_in[4];
  const float* Wv = (const float*)d_in[5];
  const float* bv = (const float*)d_in[6];
  const float* Wo = (const float*)d_in[7];
  const float* bo = (const float*)d_in[8];
  float* out = (float*)d_out;

  ushort_t* ws = (ushort_t*)d_ws;
  const size_t NE = (size_t)B_ * S_ * D_;
  const size_t NW = (size_t)D_ * D_;
  ushort_t* xb  = ws;
  ushort_t* Wqb = ws + NE;
  ushort_t* Wkb = Wqb + NW;
  ushort_t* Wvb = Wkb + NW;
  ushort_t* Wob = Wvb + NW;
  ushort_t* Qw  = Wob + NW;
  ushort_t* Kw  = Qw + NE;
  ushort_t* Vw  = Kw + NE;   // holds V^T (b,h,dk,s)
  ushort_t* Cw  = xb;

  const int XB = (int)(NE / 8 / 256);
  const int WB = (int)(NW / 8 / 256);
  cvt_all<<<dim3(XB + 4 * WB), dim3(256), 0, stream>>>(x, Wq, Wk, Wv, Wo, ws);

  gemmQKV<<<dim3(768), dim3(512), 0, stream>>>(xb, Wqb, Wkb, Wvb, bq, bk, bv, Qw, Kw, Vw);
  attn_kern<<<dim3(512), dim3(256), 0, stream>>>(Qw, Kw, Vw, Cw);
  gemmOut<<<dim3(256), dim3(512), 0, stream>>>(Cw, Wob, bo, out);
}

// Round 7
// 404.295 us; speedup vs baseline: 1.0343x; 1.0343x over previous
//
#include <hip/hip_runtime.h>
#include <hip/hip_bf16.h>
#include <cstdint>

#define B_  4
#define S_  2048
#define D_  2048
#define H_  16
#define DK_ 128

typedef __attribute__((ext_vector_type(8))) short short8;
typedef __attribute__((ext_vector_type(4))) short s16x4;
typedef __attribute__((ext_vector_type(4))) float f32x4;
typedef unsigned short ushort_t;

__device__ __forceinline__ void gl_lds16(const void* g, void* l) {
  __builtin_amdgcn_global_load_lds(
      (const __attribute__((address_space(1))) uint32_t*)g,
      (__attribute__((address_space(3))) uint32_t*)l, 16, 0, 0);
}

__device__ __forceinline__ ushort_t f2bf(float f) {
  __hip_bfloat16 h = __float2bfloat16(f);
  return *(ushort_t*)&h;
}

// ---------------------------------------------------------------------------
// fused fp32 -> bf16 conversion for x + 4 weight matrices (one launch).
// r23: 64B/thread (4x float4 load, 2x short8 store), grid 8192 (was 16384 at
// 32B/thread) — halves per-byte instruction/launch overhead.  Isolated kernel.
// ---------------------------------------------------------------------------
__global__ __launch_bounds__(256) void cvt_all(
    const float* __restrict__ x,  const float* __restrict__ w0,
    const float* __restrict__ w1, const float* __restrict__ w2,
    const float* __restrict__ w3, ushort_t* __restrict__ dst)
{
  constexpr size_t NE = (size_t)B_ * S_ * D_;
  constexpr size_t NW = (size_t)D_ * D_;
  constexpr int XB = (int)(NE / 16 / 256);   // 4096
  constexpr int WB = (int)(NW / 16 / 256);   // 1024

  const int blk = blockIdx.x;
  const float* src;
  size_t base;                                // in short8 units
  int li;
  if (blk < XB)           { src = x;  base = 0;           li = blk * 256 + threadIdx.x; }
  else if (blk < XB+WB)   { src = w0; base = NE/8;        li = (blk-XB)     * 256 + threadIdx.x; }
  else if (blk < XB+2*WB) { src = w1; base = (NE+NW)/8;   li = (blk-XB-WB)  * 256 + threadIdx.x; }
  else if (blk < XB+3*WB) { src = w2; base = (NE+2*NW)/8; li = (blk-XB-2*WB)* 256 + threadIdx.x; }
  else                    { src = w3; base = (NE+3*NW)/8; li = (blk-XB-3*WB)* 256 + threadIdx.x; }

  const float4* s4 = (const float4*)src;
  float4 a = s4[li * 4];
  float4 b = s4[li * 4 + 1];
  float4 c = s4[li * 4 + 2];
  float4 d = s4[li * 4 + 3];
  short8 o0, o1;
  o0[0] = (short)f2bf(a.x); o0[1] = (short)f2bf(a.y);
  o0[2] = (short)f2bf(a.z); o0[3] = (short)f2bf(a.w);
  o0[4] = (short)f2bf(b.x); o0[5] = (short)f2bf(b.y);
  o0[6] = (short)f2bf(b.z); o0[7] = (short)f2bf(b.w);
  o1[0] = (short)f2bf(c.x); o1[1] = (short)f2bf(c.y);
  o1[2] = (short)f2bf(c.z); o1[3] = (short)f2bf(c.w);
  o1[4] = (short)f2bf(d.x); o1[5] = (short)f2bf(d.y);
  o1[6] = (short)f2bf(d.z); o1[7] = (short)f2bf(d.w);
  ((short8*)dst)[base + li * 2]     = o0;
  ((short8*)dst)[base + li * 2 + 1] = o1;
}

// ---------------------------------------------------------------------------
// 256x256 / BK=64 / 8-wave / 4-phase GEMM — EXACT round-0 body (verified
// 215 us / MfmaUtil 40.6%; 196 us with r20 epilogue).  Single 64KB LDS
// buffer, phase-granular region recycling:
//   region death: A(q0),B(q0) after phA reads; B(q1) after phB; A(q1) after phC
//   stage tile t+1: {A(q0),B(q0)}@phB, B(q1)@phC, A(q1)@phD
//   waits (loads): phA-end vmcnt(2); phB-end vmcnt(4)|0; phD-end vmcnt(4)|0
// r17/r18 (8-phase dbuf) and r19 (merged phases) all regressed -> this body
// is the local optimum at 2 waves/SIMD.  DO NOT restructure the loop.
// r21 (proj fastest-varying) regressed: per-XCD L2 working set tripled.
// Keep proj OUTERMOST (r13 ordering).
// ---------------------------------------------------------------------------
#define STAGE_A(q, tt) do {                                                \
    int r0_ = (q) * 64 + w * 8;                                            \
    gl_lds16(Agb + (size_t)(r0_ + lr) * 2048 + (tt) * 64 + lc, &As[r0_ * 64]); \
    r0_ += 128;                                                            \
    gl_lds16(Agb + (size_t)(r0_ + lr) * 2048 + (tt) * 64 + lc, &As[r0_ * 64]); \
  } while (0)
#define STAGE_B(q, tt) do {                                                \
    int r0_ = (w >> 1) * 64 + (q) * 32 + ((w & 1) * 2) * 8;                \
    gl_lds16(Wgb + (size_t)(r0_ + lr) * 2048 + (tt) * 64 + lc, &Bs[r0_ * 64]); \
    r0_ += 8;                                                              \
    gl_lds16(Wgb + (size_t)(r0_ + lr) * 2048 + (tt) * 64 + lc, &Bs[r0_ * 64]); \
  } while (0)

#define GEMM_BODY()                                                               \
  f32x4 acc[8][4] = {};                                                           \
  short8 aA[4][2];                                                                \
  short8 bB[2][2][2];                                                             \
  STAGE_A(0, 0); STAGE_A(1, 0); STAGE_B(0, 0); STAGE_B(1, 0);                     \
  asm volatile("s_waitcnt vmcnt(0)" ::: "memory");                                \
  __builtin_amdgcn_s_barrier();                                                   \
  for (int kt = 0; kt < NT; ++kt) {                                               \
    /* phase A : read A(q0), B(q0); compute quadrant (qm0,qn0) */                 \
    _Pragma("unroll")                                                             \
    for (int fm = 0; fm < 4; ++fm)                                                \
      _Pragma("unroll")                                                           \
      for (int kk = 0; kk < 2; ++kk) {                                            \
        const int row = wm * 128 + fm * 16 + l15;                                 \
        aA[fm][kk] = *(const short8*)&As[row * 64 + (((kk * 4 + lhi) ^ (l15 & 7)) << 3)]; \
      }                                                                           \
    _Pragma("unroll")                                                             \
    for (int fn = 0; fn < 2; ++fn)                                                \
      _Pragma("unroll")                                                           \
      for (int kk = 0; kk < 2; ++kk) {                                            \
        const int row = wn * 64 + fn * 16 + l15;                                  \
        bB[0][fn][kk] = *(const short8*)&Bs[row * 64 + (((kk * 4 + lhi) ^ (l15 & 7)) << 3)]; \
      }                                                                           \
    __builtin_amdgcn_s_barrier();                                                 \
    __builtin_amdgcn_s_setprio(1);                                                \
    _Pragma("unroll")                                                             \
    for (int kk = 0; kk < 2; ++kk)                                                \
      _Pragma("unroll")                                                           \
      for (int fm = 0; fm < 4; ++fm)                                              \
        _Pragma("unroll")                                                         \
        for (int fn = 0; fn < 2; ++fn)                                            \
          acc[fm][fn] = __builtin_amdgcn_mfma_f32_16x16x32_bf16(aA[fm][kk], bB[0][fn][kk], acc[fm][fn], 0, 0, 0); \
    __builtin_amdgcn_s_setprio(0);                                                \
    asm volatile("s_waitcnt vmcnt(2)" ::: "memory");  /* force B(t,q1) */         \
    __builtin_amdgcn_s_barrier();                                                 \
    /* phase B : read B(q1); stage A(t+1,q0)+B(t+1,q0); quadrant (qm0,qn1) */     \
    _Pragma("unroll")                                                             \
    for (int fn = 0; fn < 2; ++fn)                                                \
      _Pragma("unroll")                                                           \
      for (int kk = 0; kk < 2; ++kk) {                                            \
        const int row = wn * 64 + 32 + fn * 16 + l15;                             \
        bB[1][fn][kk] = *(const short8*)&Bs[row * 64 + (((kk * 4 + lhi) ^ (l15 & 7)) << 3)]; \
      }                                                                           \
    if (kt + 1 < NT) { STAGE_A(0, kt + 1); STAGE_B(0, kt + 1); }                  \
    __builtin_amdgcn_s_barrier();                                                 \
    __builtin_amdgcn_s_setprio(1);                                                \
    _Pragma("unroll")                                                             \
    for (int kk = 0; kk < 2; ++kk)                                                \
      _Pragma("unroll")                                                           \
      for (int fm = 0; fm < 4; ++fm)                                              \
        _Pragma("unroll")                                                         \
        for (int fn = 0; fn < 2; ++fn)                                            \
          acc[fm][2 + fn] = __builtin_amdgcn_mfma_f32_16x16x32_bf16(aA[fm][kk], bB[1][fn][kk], acc[fm][2 + fn], 0, 0, 0); \
    __builtin_amdgcn_s_setprio(0);                                                \
    if (kt + 1 < NT) { asm volatile("s_waitcnt vmcnt(4)" ::: "memory"); }         \
    else             { asm volatile("s_waitcnt vmcnt(0)" ::: "memory"); }         \
    __builtin_amdgcn_s_barrier();      /* A(t,q1) now forced */                   \
    /* phase C : read A(q1); stage B(t+1,q1); quadrant (qm1,qn0) */               \
    _Pragma("unroll")                                                             \
    for (int fm = 0; fm < 4; ++fm)                                                \
      _Pragma("unroll")                                                           \
      for (int kk = 0; kk < 2; ++kk) {                                            \
        const int row = wm * 128 + 64 + fm * 16 + l15;                            \
        aA[fm][kk] = *(const short8*)&As[row * 64 + (((kk * 4 + lhi) ^ (l15 & 7)) << 3)]; \
      }                                                                           \
    if (kt + 1 < NT) STAGE_B(1, kt + 1);                                          \
    __builtin_amdgcn_s_barrier();                                                 \
    __builtin_amdgcn_s_setprio(1);                                                \
    _Pragma("unroll")                                                             \
    for (int kk = 0; kk < 2; ++kk)                                                \
      _Pragma("unroll")                                                           \
      for (int fm = 0; fm < 4; ++fm)                                              \
        _Pragma("unroll")                                                         \
        for (int fn = 0; fn < 2; ++fn)                                            \
          acc[4 + fm][fn] = __builtin_amdgcn_mfma_f32_16x16x32_bf16(aA[fm][kk], bB[0][fn][kk], acc[4 + fm][fn], 0, 0, 0); \
    __builtin_amdgcn_s_setprio(0);                                                \
    __builtin_amdgcn_s_barrier();                                                 \
    /* phase D : stage A(t+1,q1); quadrant (qm1,qn1) */                           \
    if (kt + 1 < NT) STAGE_A(1, kt + 1);                                          \
    __builtin_amdgcn_s_setprio(1);                                                \
    _Pragma("unroll")                                                             \
    for (int kk = 0; kk < 2; ++kk)                                                \
      _Pragma("unroll")                                                           \
      for (int fm = 0; fm < 4; ++fm)                                              \
        _Pragma("unroll")                                                         \
        for (int fn = 0; fn < 2; ++fn)                                            \
          acc[4 + fm][2 + fn] = __builtin_amdgcn_mfma_f32_16x16x32_bf16(aA[fm][kk], bB[1][fn][kk], acc[4 + fm][2 + fn], 0, 0, 0); \
    __builtin_amdgcn_s_setprio(0);                                                \
    if (kt + 1 < NT) { asm volatile("s_waitcnt vmcnt(4)" ::: "memory"); }         \
    else             { asm volatile("s_waitcnt vmcnt(0)" ::: "memory"); }         \
    __builtin_amdgcn_s_barrier();      /* A/B(t+1,q0) now forced */               \
  }

// ---------------------------------------------------------------------------
// Fused QKV projection GEMM. Grid 768 (r13 L2-aware swizzle, proj OUTERMOST).
// r20: Q/K epilogue routed through LDS transpose (As dead post-loop) ->
// dk-contiguous short8 stores (WRITE_SIZE 180->104MB).  V path unchanged.
// ---------------------------------------------------------------------------
__global__ __launch_bounds__(512, 2) void gemmQKV(
    const ushort_t* __restrict__ A,
    const ushort_t* __restrict__ Wqm, const ushort_t* __restrict__ Wkm,
    const ushort_t* __restrict__ Wvm,
    const float* __restrict__ bq, const float* __restrict__ bk,
    const float* __restrict__ bv,
    ushort_t* __restrict__ Qo, ushort_t* __restrict__ Ko,
    ushort_t* __restrict__ Vo)
{
  constexpr int NT = D_ / 64;

  __shared__ ushort_t As[256 * 64];
  __shared__ ushort_t Bs[256 * 64];

  const int bid = blockIdx.x;
  const int c = bid & 7;
  const int j0 = bid >> 3;                // 0..95
  const int proj = j0 >> 5;               // 0..2  (outermost)
  const int s = j0 & 31;
  const int tnl = s & 7;
  const int tm = c * 4 + (s >> 3);

  const ushort_t* Wsel = (proj == 0) ? Wqm : (proj == 1) ? Wkm : Wvm;
  const float*    bsel = (proj == 0) ? bq  : (proj == 1) ? bk  : bv;
  ushort_t*       osel = (proj == 0) ? Qo  : (proj == 1) ? Ko  : Vo;

  const int t = threadIdx.x;
  const int l = t & 63;
  const int w = t >> 6;
  const int wm = w >> 2;
  const int wn = w & 3;
  const int l15 = l & 15, lhi = l >> 4;
  const int lr = l >> 3;
  const int lc = ((l & 7) ^ lr) * 8;

  const ushort_t* Agb = A + (size_t)(tm * 256) * 2048;
  const ushort_t* Wgb = Wsel + (size_t)(tnl * 256) * 2048;

  GEMM_BODY()

  if (proj == 2) {
    // V: store V^T (b,h,dk,s) — s16x4 packs give dense 128B coverage already.
#pragma unroll
    for (int qn = 0; qn < 2; ++qn)
#pragma unroll
      for (int fn = 0; fn < 2; ++fn) {
        const int e = tnl * 256 + wn * 64 + qn * 32 + fn * 16 + l15;
        const float bvv = bsel[e];
        const int h = e >> 7, dk = e & (DK_ - 1);
#pragma unroll
        for (int qm = 0; qm < 2; ++qm)
#pragma unroll
          for (int fm = 0; fm < 4; ++fm) {
            const int srow0 = tm * 256 + wm * 128 + qm * 64 + fm * 16 + lhi * 4;
            const f32x4 v4 = acc[qm * 4 + fm][qn * 2 + fn];
            const int b = srow0 >> 11, s0 = srow0 & (S_ - 1);
            s16x4 pk;
#pragma unroll
            for (int r = 0; r < 4; ++r) pk[r] = (short)f2bf(v4[r] + bvv);
            *(s16x4*)(osel + (((size_t)b * H_ + h) * DK_ + dk) * S_ + s0) = pk;
          }
      }
  } else {
    // Q/K: per (qm,qn) 128x128 chunk, acc -> LDS (bank-swizzled) -> short8
    // dk-contiguous stores.
#pragma unroll
    for (int qm = 0; qm < 2; ++qm)
#pragma unroll
      for (int qn = 0; qn < 2; ++qn) {
        __syncthreads();   // previous chunk fully read (no-op cost 1st iter)
#pragma unroll
        for (int fn = 0; fn < 2; ++fn) {
          const int e = tnl * 256 + wn * 64 + qn * 32 + fn * 16 + l15;
          const float bvv = bsel[e];
          const int lcol = wn * 32 + fn * 16 + l15;
#pragma unroll
          for (int fm = 0; fm < 4; ++fm) {
            const f32x4 v4 = acc[qm * 4 + fm][qn * 2 + fn];
#pragma unroll
            for (int r = 0; r < 4; ++r) {
              const int lrow = wm * 64 + fm * 16 + lhi * 4 + r;
              As[lrow * 128 + (lcol ^ ((lrow & 7) << 3))] = f2bf(v4[r] + bvv);
            }
          }
        }
        __syncthreads();   // writes visible
        {
          const int erow = t >> 2;          // 0..127 chunk-local row
          const int eli  = t & 3;           // 8-dk segment within 32-col block
          const int grow = tm * 256 + (erow >> 6) * 128 + qm * 64 + (erow & 63);
          const int bb = grow >> 11, sR = grow & (S_ - 1);
#pragma unroll
          for (int wnb = 0; wnb < 4; ++wnb) {
            const int lcol = wnb * 32 + eli * 8;
            short8 v = *(const short8*)&As[erow * 128 + (lcol ^ ((erow & 7) << 3))];
            const int col = wnb * 64 + qn * 32 + eli * 8;
            const int e2 = tnl * 256 + col;
            const int h = e2 >> 7, dk = e2 & (DK_ - 1);
            *(short8*)(osel + (((size_t)bb * H_ + h) * S_ + sR) * DK_ + dk) = v;
          }
        }
      }
  }
}

// ---------------------------------------------------------------------------
// Output projection GEMM: fp32 MxN. grid 256.  (fp32 stores are already
// 64B-dense per 16-lane group — no epilogue change.)
// ---------------------------------------------------------------------------
__global__ __launch_bounds__(512, 2) void gemmOut(
    const ushort_t* __restrict__ A,
    const ushort_t* __restrict__ W,
    const float* __restrict__ bias,
    float* __restrict__ outp)
{
  constexpr int NT = D_ / 64;
  constexpr int NWG = (B_ * S_ / 256) * (D_ / 256);

  __shared__ ushort_t As[256 * 64];
  __shared__ ushort_t Bs[256 * 64];

  const int bid = blockIdx.x;
  const int swz = (bid & 7) * (NWG / 8) + (bid >> 3);
  const int tm = swz >> 3;
  const int tn = swz & 7;

  const int t = threadIdx.x;
  const int l = t & 63;
  const int w = t >> 6;
  const int wm = w >> 2;
  const int wn = w & 3;
  const int l15 = l & 15, lhi = l >> 4;
  const int lr = l >> 3;
  const int lc = ((l & 7) ^ lr) * 8;

  const ushort_t* Agb = A + (size_t)(tm * 256) * 2048;
  const ushort_t* Wgb = W + (size_t)(tn * 256) * 2048;

  GEMM_BODY()

#pragma unroll
  for (int qn = 0; qn < 2; ++qn)
#pragma unroll
    for (int fn = 0; fn < 2; ++fn) {
      const int e = tn * 256 + wn * 64 + qn * 32 + fn * 16 + l15;
      const float bvv = bias[e];
#pragma unroll
      for (int qm = 0; qm < 2; ++qm)
#pragma unroll
        for (int fm = 0; fm < 4; ++fm) {
          const int srow0 = tm * 256 + wm * 128 + qm * 64 + fm * 16 + lhi * 4;
          const f32x4 v4 = acc[qm * 4 + fm][qn * 2 + fn];
#pragma unroll
          for (int r = 0; r < 4; ++r)
            outp[(size_t)(srow0 + r) * D_ + e] = v4[r] + bvv;
        }
    }
}
#undef STAGE_A
#undef STAGE_B
#undef GEMM_BODY

// ---------------------------------------------------------------------------
// Causal flash attention — exact r10 version (double-buffered K/V LDS, 128-row
// blocks, ones-MFMA row-sum, swizzled P stride-64, (256,2), grid 512).
// r22 (C-write via LDS) regressed 16us (botched lane mapping + 3x epilogue
// inst count; ceiling was only ~5us) -> reverted to scalar C stores.
// ---------------------------------------------------------------------------
__global__ __launch_bounds__(256, 2) void attn_kern(
    const ushort_t* __restrict__ Q,
    const ushort_t* __restrict__ K,
    const ushort_t* __restrict__ Vt,
    ushort_t* __restrict__ C)
{
  __shared__ ushort_t Ks[2][64 * 128];
  __shared__ ushort_t Vs[2][128 * 64];
  __shared__ ushort_t Pl[4][32 * 64];

  const int bid = blockIdx.x;
  const int i = bid >> 3;
  const int bh = (bid & 7) * 8 + (i >> 3);
  const int qp = i & 7;

  const ushort_t* Qg = Q + (size_t)bh * S_ * DK_;
  const ushort_t* Kg = K + (size_t)bh * S_ * DK_;
  const ushort_t* Vg = Vt + (size_t)bh * DK_ * S_;
  const int b = bh >> 4, h = bh & 15;

  const int t = threadIdx.x;
  const int l = t & 63;
  const int w = t >> 6;
  const int l15 = l & 15, lhi = l >> 4;

  const float cs = 0.08838834764831845f * 1.4426950408889634f;
  const float DEFER_RAW = 8.0f / cs;

  short8 ones;
#pragma unroll
  for (int j = 0; j < 8; ++j) ones[j] = (short)0x3F80;

  int koff[4], voff[4];
#pragma unroll
  for (int j = 0; j < 4; ++j) {
    const int krow = w * 16 + j * 4 + lhi;
    koff[j] = krow * DK_ + 8 * (l15 ^ ((j * 4 + lhi) & 7));
    const int vrow = (w * 4 + j) * 8 + (l >> 3);
    voff[j] = vrow * S_ + 8 * ((l & 7) ^ (l >> 3));
  }
  int kcol[4];
#pragma unroll
  for (int kt = 0; kt < 4; ++kt)
    kcol[kt] = ((kt * 64 + lhi * 16) ^ ((l15 & 7) << 4)) >> 1;
  int vcol[2];
#pragma unroll
  for (int hb = 0; hb < 2; ++hb)
    vcol[hb] = ((hb * 64 + lhi * 16) ^ ((l15 & 7) << 4)) >> 1;

#define STAGE_KV(pb, kvv) do {                                              \
    _Pragma("unroll")                                                       \
    for (int j = 0; j < 4; ++j) {                                           \
      gl_lds16(Kg + (size_t)(kvv) * DK_ + koff[j], Ks[pb] + (w * 4 + j) * 512); \
      gl_lds16(Vg + (size_t)(kvv) + voff[j],       Vs[pb] + (w * 4 + j) * 512); \
    }                                                                       \
  } while (0)

  for (int pass = 0; pass < 2; ++pass) {
    const int qb = pass ? (15 - qp) : qp;
    const int qrow0 = qb * 128 + w * 32;
    const int nkv = 2 * (qb + 1);

    short8 qa[2][4];
#pragma unroll
    for (int rf = 0; rf < 2; ++rf)
#pragma unroll
      for (int kt = 0; kt < 4; ++kt)
        qa[rf][kt] = *(const short8*)(Qg + (size_t)(qrow0 + rf * 16 + l15) * DK_ + kt * 32 + lhi * 8);

    f32x4 o[2][8] = {};
    f32x4 lsum[2] = {};
    float mrow[2][4];
#pragma unroll
    for (int rf = 0; rf < 2; ++rf)
#pragma unroll
      for (int r = 0; r < 4; ++r) mrow[rf][r] = -1e30f;

    STAGE_KV(0, 0);
    asm volatile("s_waitcnt vmcnt(0)" ::: "memory");
    __syncthreads();

    for (int kvt = 0; kvt < nkv; ++kvt) {
      const int kv = kvt * 64;
      const int p = kvt & 1;

      if (kvt + 1 < nkv) STAGE_KV(p ^ 1, kv + 64);

      f32x4 sf[2][4] = {};
      __builtin_amdgcn_s_setprio(1);
#pragma unroll
      for (int f = 0; f < 4; ++f) {
#pragma unroll
        for (int kt = 0; kt < 4; ++kt) {
          short8 kb = *(const short8*)(Ks[p] + (f * 16 + l15) * 128 + kcol[kt]);
          sf[0][f] = __builtin_amdgcn_mfma_f32_16x16x32_bf16(qa[0][kt], kb, sf[0][f], 0, 0, 0);
          sf[1][f] = __builtin_amdgcn_mfma_f32_16x16x32_bf16(qa[1][kt], kb, sf[1][f], 0, 0, 0);
        }
      }
      __builtin_amdgcn_s_setprio(0);

      float pmax[2][4];
#pragma unroll
      for (int rf = 0; rf < 2; ++rf)
#pragma unroll
        for (int r = 0; r < 4; ++r) pmax[rf][r] = -1e30f;
      const bool domask = (kv + 63 > qrow0);
      if (domask) {
#pragma unroll
        for (int f = 0; f < 4; ++f) {
          const int col = kv + f * 16 + l15;
#pragma unroll
          for (int rf = 0; rf < 2; ++rf)
#pragma unroll
            for (int r = 0; r < 4; ++r) {
              const int row = qrow0 + rf * 16 + lhi * 4 + r;
              if (col > row) sf[rf][f][r] = -1e30f;
              pmax[rf][r] = fmaxf(pmax[rf][r], sf[rf][f][r]);
            }
        }
      } else {
#pragma unroll
        for (int f = 0; f < 4; ++f)
#pragma unroll
          for (int rf = 0; rf < 2; ++rf)
#pragma unroll
            for (int r = 0; r < 4; ++r)
              pmax[rf][r] = fmaxf(pmax[rf][r], sf[rf][f][r]);
      }
#pragma unroll
      for (int d = 1; d < 16; d <<= 1)
#pragma unroll
        for (int rf = 0; rf < 2; ++rf)
#pragma unroll
          for (int r = 0; r < 4; ++r)
            pmax[rf][r] = fmaxf(pmax[rf][r], __shfl_xor(pmax[rf][r], d, 64));

      bool need = false;
#pragma unroll
      for (int rf = 0; rf < 2; ++rf)
#pragma unroll
        for (int r = 0; r < 4; ++r) need |= (pmax[rf][r] > mrow[rf][r] + DEFER_RAW);
      if (__any(need)) {
#pragma unroll
        for (int rf = 0; rf < 2; ++rf)
#pragma unroll
          for (int r = 0; r < 4; ++r) {
            const float mn = fmaxf(mrow[rf][r], pmax[rf][r]);
            const float alpha = __builtin_amdgcn_exp2f((mrow[rf][r] - mn) * cs);
            mrow[rf][r] = mn;
            lsum[rf][r] *= alpha;
#pragma unroll
            for (int n = 0; n < 8; ++n) o[rf][n][r] *= alpha;
          }
      }

      ushort_t* P = Pl[w];
#pragma unroll
      for (int f = 0; f < 4; ++f)
#pragma unroll
        for (int rf = 0; rf < 2; ++rf)
#pragma unroll
          for (int r = 0; r < 4; ++r) {
            const float pv = __builtin_amdgcn_exp2f((sf[rf][f][r] - mrow[rf][r]) * cs);
            const int prow = rf * 16 + lhi * 4 + r;
            P[prow * 64 + ((f * 16 + l15) ^ ((prow & 7) << 3))] = f2bf(pv);
          }

      asm volatile("s_waitcnt lgkmcnt(0)" ::: "memory");
      short8 pa[2][2];
#pragma unroll
      for (int rf = 0; rf < 2; ++rf)
#pragma unroll
        for (int ks = 0; ks < 2; ++ks) {
          const int prow = rf * 16 + l15;
          pa[rf][ks] = *(const short8*)(P + prow * 64 + ((ks * 32 + lhi * 8) ^ ((prow & 7) << 3)));
        }

      __builtin_amdgcn_s_setprio(1);
#pragma unroll
      for (int rf = 0; rf < 2; ++rf) {
        lsum[rf] = __builtin_amdgcn_mfma_f32_16x16x32_bf16(pa[rf][0], ones, lsum[rf], 0, 0, 0);
        lsum[rf] = __builtin_amdgcn_mfma_f32_16x16x32_bf16(pa[rf][1], ones, lsum[rf], 0, 0, 0);
      }
#pragma unroll
      for (int n = 0; n < 8; ++n) {
#pragma unroll
        for (int hb = 0; hb < 2; ++hb) {
          short8 vb = *(const short8*)(Vs[p] + (n * 16 + l15) * 64 + vcol[hb]);
          o[0][n] = __builtin_amdgcn_mfma_f32_16x16x32_bf16(pa[0][hb], vb, o[0][n], 0, 0, 0);
          o[1][n] = __builtin_amdgcn_mfma_f32_16x16x32_bf16(pa[1][hb], vb, o[1][n], 0, 0, 0);
        }
      }
      __builtin_amdgcn_s_setprio(0);

      asm volatile("s_waitcnt vmcnt(0)" ::: "memory");
      __syncthreads();
    }

#pragma unroll
    for (int rf = 0; rf < 2; ++rf) {
      float linv[4];
#pragma unroll
      for (int r = 0; r < 4; ++r) linv[r] = 1.0f / lsum[rf][r];
#pragma unroll
      for (int n = 0; n < 8; ++n) {
        const int dk = n * 16 + l15;
#pragma unroll
        for (int r = 0; r < 4; ++r) {
          const int srow = qrow0 + rf * 16 + lhi * 4 + r;
          C[(((size_t)b * S_ + srow) * H_ + h) * DK_ + dk] = f2bf(o[rf][n][r] * linv[r]);
        }
      }
    }
  }
#undef STAGE_KV
}

// ---------------------------------------------------------------------------
extern "C" void kernel_launch(void* const* d_in, const int* in_sizes, int n_in,
                              void* d_out, int out_size, void* d_ws, size_t ws_size,
                              hipStream_t stream) {
  const float* x  = (const float*)d_in[0];
  const float* Wq = (const float*)d_in[1];
  const float* bq = (const float*)d_in[2];
  const float* Wk = (const float*)d_in[3];
  const float* bk = (const float*)d_in[4];
  const float* Wv = (const float*)d_in[5];
  const float* bv = (const float*)d_in[6];
  const float* Wo = (const float*)d_in[7];
  const float* bo = (const float*)d_in[8];
  float* out = (float*)d_out;

  ushort_t* ws = (ushort_t*)d_ws;
  const size_t NE = (size_t)B_ * S_ * D_;
  const size_t NW = (size_t)D_ * D_;
  ushort_t* xb  = ws;
  ushort_t* Wqb = ws + NE;
  ushort_t* Wkb = Wqb + NW;
  ushort_t* Wvb = Wkb + NW;
  ushort_t* Wob = Wvb + NW;
  ushort_t* Qw  = Wob + NW;
  ushort_t* Kw  = Qw + NE;
  ushort_t* Vw  = Kw + NE;   // holds V^T (b,h,dk,s)
  ushort_t* Cw  = xb;

  const int XB = (int)(NE / 16 / 256);
  const int WB = (int)(NW / 16 / 256);
  cvt_all<<<dim3(XB + 4 * WB), dim3(256), 0, stream>>>(x, Wq, Wk, Wv, Wo, ws);

  gemmQKV<<<dim3(768), dim3(512), 0, stream>>>(xb, Wqb, Wkb, Wvb, bq, bk, bv, Qw, Kw, Vw);
  attn_kern<<<dim3(512), dim3(256), 0, stream>>>(Qw, Kw, Vw, Cw);
  gemmOut<<<dim3(256), dim3(512), 0, stream>>>(Cw, Wob, bo, out);
}

// Round 8
// 399.530 us; speedup vs baseline: 1.0467x; 1.0119x over previous
//
#include <hip/hip_runtime.h>
#include <hip/hip_bf16.h>
#include <cstdint>

#define B_  4
#define S_  2048
#define D_  2048
#define H_  16
#define DK_ 128

typedef __attribute__((ext_vector_type(8))) short short8;
typedef __attribute__((ext_vector_type(4))) short s16x4;
typedef __attribute__((ext_vector_type(4))) float f32x4;
typedef unsigned short ushort_t;

__device__ __forceinline__ void gl_lds16(const void* g, void* l) {
  __builtin_amdgcn_global_load_lds(
      (const __attribute__((address_space(1))) uint32_t*)g,
      (__attribute__((address_space(3))) uint32_t*)l, 16, 0, 0);
}

__device__ __forceinline__ ushort_t f2bf(float f) {
  __hip_bfloat16 h = __float2bfloat16(f);
  return *(ushort_t*)&h;
}

// ---------------------------------------------------------------------------
// fused fp32 -> bf16 conversion for x + 4 weight matrices (one launch).
// (round-4 exact: 32B/thread.  r23's 64B/thread was neutral — reverted for
// provenance to the session-best 402.4us configuration.)
// ---------------------------------------------------------------------------
__global__ __launch_bounds__(256) void cvt_all(
    const float* __restrict__ x,  const float* __restrict__ w0,
    const float* __restrict__ w1, const float* __restrict__ w2,
    const float* __restrict__ w3, ushort_t* __restrict__ dst)
{
  constexpr size_t NE = (size_t)B_ * S_ * D_;
  constexpr size_t NW = (size_t)D_ * D_;
  constexpr int XB = (int)(NE / 8 / 256);
  constexpr int WB = (int)(NW / 8 / 256);

  const int blk = blockIdx.x;
  const float* src;
  size_t base;
  int li;
  if (blk < XB)           { src = x;  base = 0;           li = blk * 256 + threadIdx.x; }
  else if (blk < XB+WB)   { src = w0; base = NE/8;        li = (blk-XB)     * 256 + threadIdx.x; }
  else if (blk < XB+2*WB) { src = w1; base = (NE+NW)/8;   li = (blk-XB-WB)  * 256 + threadIdx.x; }
  else if (blk < XB+3*WB) { src = w2; base = (NE+2*NW)/8; li = (blk-XB-2*WB)* 256 + threadIdx.x; }
  else                    { src = w3; base = (NE+3*NW)/8; li = (blk-XB-3*WB)* 256 + threadIdx.x; }

  float4 a = ((const float4*)src)[li * 2];
  float4 b = ((const float4*)src)[li * 2 + 1];
  short8 o;
  o[0] = (short)f2bf(a.x); o[1] = (short)f2bf(a.y);
  o[2] = (short)f2bf(a.z); o[3] = (short)f2bf(a.w);
  o[4] = (short)f2bf(b.x); o[5] = (short)f2bf(b.y);
  o[6] = (short)f2bf(b.z); o[7] = (short)f2bf(b.w);
  ((short8*)dst)[base + li] = o;
}

// ---------------------------------------------------------------------------
// 256x256 / BK=64 / 8-wave / 4-phase GEMM — round-0 body (verified 215us /
// MfmaUtil 40.6%; 196us with r20 epilogue).  Single 64KB LDS buffer,
// phase-granular region recycling:
//   region death: A(q0),B(q0) after phA reads; B(q1) after phB; A(q1) after phC
//   stage tile t+1: {A(q0),B(q0)}@phB, B(q1)@phC, A(q1)@phD
//   waits (loads): phA-end vmcnt(2); phB-end vmcnt(4)|0; phD-end vmcnt(4)|0
// STRUCTURE-FLOOR NOTE (session conclusion): per K-tile per CU this runs
// LDS reg-loads (~2300cyc: 192 ds_read_b128 x ~12cyc) and MFMA (~2485cyc:
// 512 mfma_16x16x32 x ~4.85cyc) ADDITIVELY (measured 4900cyc/tile = 97% of
// 2300+2485).  Overlap needs either fragment double-buffering (+32-48 VGPR,
// but acc128+frag48+addr ~= 244/wave sits exactly at the 2-wave/SIMD
// boundary -> would halve occupancy) or >1 block/CU (needs <=128 regs ->
// 128^2 tile, which measures LOWER, m103).  r17/r18 (8-phase dbuf), r19
// (merged phases) all regressed 28-50us.  DO NOT restructure this loop.
// r21 (proj fastest-varying) regressed: per-XCD L2 working set tripled.
// ---------------------------------------------------------------------------
#define STAGE_A(q, tt) do {                                                \
    int r0_ = (q) * 64 + w * 8;                                            \
    gl_lds16(Agb + (size_t)(r0_ + lr) * 2048 + (tt) * 64 + lc, &As[r0_ * 64]); \
    r0_ += 128;                                                            \
    gl_lds16(Agb + (size_t)(r0_ + lr) * 2048 + (tt) * 64 + lc, &As[r0_ * 64]); \
  } while (0)
#define STAGE_B(q, tt) do {                                                \
    int r0_ = (w >> 1) * 64 + (q) * 32 + ((w & 1) * 2) * 8;                \
    gl_lds16(Wgb + (size_t)(r0_ + lr) * 2048 + (tt) * 64 + lc, &Bs[r0_ * 64]); \
    r0_ += 8;                                                              \
    gl_lds16(Wgb + (size_t)(r0_ + lr) * 2048 + (tt) * 64 + lc, &Bs[r0_ * 64]); \
  } while (0)

#define GEMM_BODY()                                                               \
  f32x4 acc[8][4] = {};                                                           \
  short8 aA[4][2];                                                                \
  short8 bB[2][2][2];                                                             \
  STAGE_A(0, 0); STAGE_A(1, 0); STAGE_B(0, 0); STAGE_B(1, 0);                     \
  asm volatile("s_waitcnt vmcnt(0)" ::: "memory");                                \
  __builtin_amdgcn_s_barrier();                                                   \
  for (int kt = 0; kt < NT; ++kt) {                                               \
    /* phase A : read A(q0), B(q0); compute quadrant (qm0,qn0) */                 \
    _Pragma("unroll")                                                             \
    for (int fm = 0; fm < 4; ++fm)                                                \
      _Pragma("unroll")                                                           \
      for (int kk = 0; kk < 2; ++kk) {                                            \
        const int row = wm * 128 + fm * 16 + l15;                                 \
        aA[fm][kk] = *(const short8*)&As[row * 64 + (((kk * 4 + lhi) ^ (l15 & 7)) << 3)]; \
      }                                                                           \
    _Pragma("unroll")                                                             \
    for (int fn = 0; fn < 2; ++fn)                                                \
      _Pragma("unroll")                                                           \
      for (int kk = 0; kk < 2; ++kk) {                                            \
        const int row = wn * 64 + fn * 16 + l15;                                  \
        bB[0][fn][kk] = *(const short8*)&Bs[row * 64 + (((kk * 4 + lhi) ^ (l15 & 7)) << 3)]; \
      }                                                                           \
    __builtin_amdgcn_s_barrier();                                                 \
    __builtin_amdgcn_s_setprio(1);                                                \
    _Pragma("unroll")                                                             \
    for (int kk = 0; kk < 2; ++kk)                                                \
      _Pragma("unroll")                                                           \
      for (int fm = 0; fm < 4; ++fm)                                              \
        _Pragma("unroll")                                                         \
        for (int fn = 0; fn < 2; ++fn)                                            \
          acc[fm][fn] = __builtin_amdgcn_mfma_f32_16x16x32_bf16(aA[fm][kk], bB[0][fn][kk], acc[fm][fn], 0, 0, 0); \
    __builtin_amdgcn_s_setprio(0);                                                \
    asm volatile("s_waitcnt vmcnt(2)" ::: "memory");  /* force B(t,q1) */         \
    __builtin_amdgcn_s_barrier();                                                 \
    /* phase B : read B(q1); stage A(t+1,q0)+B(t+1,q0); quadrant (qm0,qn1) */     \
    _Pragma("unroll")                                                             \
    for (int fn = 0; fn < 2; ++fn)                                                \
      _Pragma("unroll")                                                           \
      for (int kk = 0; kk < 2; ++kk) {                                            \
        const int row = wn * 64 + 32 + fn * 16 + l15;                             \
        bB[1][fn][kk] = *(const short8*)&Bs[row * 64 + (((kk * 4 + lhi) ^ (l15 & 7)) << 3)]; \
      }                                                                           \
    if (kt + 1 < NT) { STAGE_A(0, kt + 1); STAGE_B(0, kt + 1); }                  \
    __builtin_amdgcn_s_barrier();                                                 \
    __builtin_amdgcn_s_setprio(1);                                                \
    _Pragma("unroll")                                                             \
    for (int kk = 0; kk < 2; ++kk)                                                \
      _Pragma("unroll")                                                           \
      for (int fm = 0; fm < 4; ++fm)                                              \
        _Pragma("unroll")                                                         \
        for (int fn = 0; fn < 2; ++fn)                                            \
          acc[fm][2 + fn] = __builtin_amdgcn_mfma_f32_16x16x32_bf16(aA[fm][kk], bB[1][fn][kk], acc[fm][2 + fn], 0, 0, 0); \
    __builtin_amdgcn_s_setprio(0);                                                \
    if (kt + 1 < NT) { asm volatile("s_waitcnt vmcnt(4)" ::: "memory"); }         \
    else             { asm volatile("s_waitcnt vmcnt(0)" ::: "memory"); }         \
    __builtin_amdgcn_s_barrier();      /* A(t,q1) now forced */                   \
    /* phase C : read A(q1); stage B(t+1,q1); quadrant (qm1,qn0) */               \
    _Pragma("unroll")                                                             \
    for (int fm = 0; fm < 4; ++fm)                                                \
      _Pragma("unroll")                                                           \
      for (int kk = 0; kk < 2; ++kk) {                                            \
        const int row = wm * 128 + 64 + fm * 16 + l15;                            \
        aA[fm][kk] = *(const short8*)&As[row * 64 + (((kk * 4 + lhi) ^ (l15 & 7)) << 3)]; \
      }                                                                           \
    if (kt + 1 < NT) STAGE_B(1, kt + 1);                                          \
    __builtin_amdgcn_s_barrier();                                                 \
    __builtin_amdgcn_s_setprio(1);                                                \
    _Pragma("unroll")                                                             \
    for (int kk = 0; kk < 2; ++kk)                                                \
      _Pragma("unroll")                                                           \
      for (int fm = 0; fm < 4; ++fm)                                              \
        _Pragma("unroll")                                                         \
        for (int fn = 0; fn < 2; ++fn)                                            \
          acc[4 + fm][fn] = __builtin_amdgcn_mfma_f32_16x16x32_bf16(aA[fm][kk], bB[0][fn][kk], acc[4 + fm][fn], 0, 0, 0); \
    __builtin_amdgcn_s_setprio(0);                                                \
    __builtin_amdgcn_s_barrier();                                                 \
    /* phase D : stage A(t+1,q1); quadrant (qm1,qn1) */                           \
    if (kt + 1 < NT) STAGE_A(1, kt + 1);                                          \
    __builtin_amdgcn_s_setprio(1);                                                \
    _Pragma("unroll")                                                             \
    for (int kk = 0; kk < 2; ++kk)                                                \
      _Pragma("unroll")                                                           \
      for (int fm = 0; fm < 4; ++fm)                                              \
        _Pragma("unroll")                                                         \
        for (int fn = 0; fn < 2; ++fn)                                            \
          acc[4 + fm][2 + fn] = __builtin_amdgcn_mfma_f32_16x16x32_bf16(aA[fm][kk], bB[1][fn][kk], acc[4 + fm][2 + fn], 0, 0, 0); \
    __builtin_amdgcn_s_setprio(0);                                                \
    if (kt + 1 < NT) { asm volatile("s_waitcnt vmcnt(4)" ::: "memory"); }         \
    else             { asm volatile("s_waitcnt vmcnt(0)" ::: "memory"); }         \
    __builtin_amdgcn_s_barrier();      /* A/B(t+1,q0) now forced */               \
  }

// ---------------------------------------------------------------------------
// Fused QKV projection GEMM. Grid 768 (r13 L2-aware swizzle, proj OUTERMOST).
// r20: Q/K epilogue routed through LDS transpose (As dead post-loop) ->
// dk-contiguous short8 stores (WRITE_SIZE 180->104MB).  V path unchanged.
// ---------------------------------------------------------------------------
__global__ __launch_bounds__(512, 2) void gemmQKV(
    const ushort_t* __restrict__ A,
    const ushort_t* __restrict__ Wqm, const ushort_t* __restrict__ Wkm,
    const ushort_t* __restrict__ Wvm,
    const float* __restrict__ bq, const float* __restrict__ bk,
    const float* __restrict__ bv,
    ushort_t* __restrict__ Qo, ushort_t* __restrict__ Ko,
    ushort_t* __restrict__ Vo)
{
  constexpr int NT = D_ / 64;

  __shared__ ushort_t As[256 * 64];
  __shared__ ushort_t Bs[256 * 64];

  const int bid = blockIdx.x;
  const int c = bid & 7;
  const int j0 = bid >> 3;                // 0..95
  const int proj = j0 >> 5;               // 0..2  (outermost)
  const int s = j0 & 31;
  const int tnl = s & 7;
  const int tm = c * 4 + (s >> 3);

  const ushort_t* Wsel = (proj == 0) ? Wqm : (proj == 1) ? Wkm : Wvm;
  const float*    bsel = (proj == 0) ? bq  : (proj == 1) ? bk  : bv;
  ushort_t*       osel = (proj == 0) ? Qo  : (proj == 1) ? Ko  : Vo;

  const int t = threadIdx.x;
  const int l = t & 63;
  const int w = t >> 6;
  const int wm = w >> 2;
  const int wn = w & 3;
  const int l15 = l & 15, lhi = l >> 4;
  const int lr = l >> 3;
  const int lc = ((l & 7) ^ lr) * 8;

  const ushort_t* Agb = A + (size_t)(tm * 256) * 2048;
  const ushort_t* Wgb = Wsel + (size_t)(tnl * 256) * 2048;

  GEMM_BODY()

  if (proj == 2) {
    // V: store V^T (b,h,dk,s) — s16x4 packs give dense 128B coverage already.
#pragma unroll
    for (int qn = 0; qn < 2; ++qn)
#pragma unroll
      for (int fn = 0; fn < 2; ++fn) {
        const int e = tnl * 256 + wn * 64 + qn * 32 + fn * 16 + l15;
        const float bvv = bsel[e];
        const int h = e >> 7, dk = e & (DK_ - 1);
#pragma unroll
        for (int qm = 0; qm < 2; ++qm)
#pragma unroll
          for (int fm = 0; fm < 4; ++fm) {
            const int srow0 = tm * 256 + wm * 128 + qm * 64 + fm * 16 + lhi * 4;
            const f32x4 v4 = acc[qm * 4 + fm][qn * 2 + fn];
            const int b = srow0 >> 11, s0 = srow0 & (S_ - 1);
            s16x4 pk;
#pragma unroll
            for (int r = 0; r < 4; ++r) pk[r] = (short)f2bf(v4[r] + bvv);
            *(s16x4*)(osel + (((size_t)b * H_ + h) * DK_ + dk) * S_ + s0) = pk;
          }
      }
  } else {
    // Q/K: per (qm,qn) 128x128 chunk, acc -> LDS (bank-swizzled) -> short8
    // dk-contiguous stores.
#pragma unroll
    for (int qm = 0; qm < 2; ++qm)
#pragma unroll
      for (int qn = 0; qn < 2; ++qn) {
        __syncthreads();   // previous chunk fully read (no-op cost 1st iter)
#pragma unroll
        for (int fn = 0; fn < 2; ++fn) {
          const int e = tnl * 256 + wn * 64 + qn * 32 + fn * 16 + l15;
          const float bvv = bsel[e];
          const int lcol = wn * 32 + fn * 16 + l15;
#pragma unroll
          for (int fm = 0; fm < 4; ++fm) {
            const f32x4 v4 = acc[qm * 4 + fm][qn * 2 + fn];
#pragma unroll
            for (int r = 0; r < 4; ++r) {
              const int lrow = wm * 64 + fm * 16 + lhi * 4 + r;
              As[lrow * 128 + (lcol ^ ((lrow & 7) << 3))] = f2bf(v4[r] + bvv);
            }
          }
        }
        __syncthreads();   // writes visible
        {
          const int erow = t >> 2;          // 0..127 chunk-local row
          const int eli  = t & 3;           // 8-dk segment within 32-col block
          const int grow = tm * 256 + (erow >> 6) * 128 + qm * 64 + (erow & 63);
          const int bb = grow >> 11, sR = grow & (S_ - 1);
#pragma unroll
          for (int wnb = 0; wnb < 4; ++wnb) {
            const int lcol = wnb * 32 + eli * 8;
            short8 v = *(const short8*)&As[erow * 128 + (lcol ^ ((erow & 7) << 3))];
            const int col = wnb * 64 + qn * 32 + eli * 8;
            const int e2 = tnl * 256 + col;
            const int h = e2 >> 7, dk = e2 & (DK_ - 1);
            *(short8*)(osel + (((size_t)bb * H_ + h) * S_ + sR) * DK_ + dk) = v;
          }
        }
      }
  }
}

// ---------------------------------------------------------------------------
// Output projection GEMM: fp32 MxN. grid 256.  (fp32 stores are already
// 64B-dense per 16-lane group — no epilogue change.)
// ---------------------------------------------------------------------------
__global__ __launch_bounds__(512, 2) void gemmOut(
    const ushort_t* __restrict__ A,
    const ushort_t* __restrict__ W,
    const float* __restrict__ bias,
    float* __restrict__ outp)
{
  constexpr int NT = D_ / 64;
  constexpr int NWG = (B_ * S_ / 256) * (D_ / 256);

  __shared__ ushort_t As[256 * 64];
  __shared__ ushort_t Bs[256 * 64];

  const int bid = blockIdx.x;
  const int swz = (bid & 7) * (NWG / 8) + (bid >> 3);
  const int tm = swz >> 3;
  const int tn = swz & 7;

  const int t = threadIdx.x;
  const int l = t & 63;
  const int w = t >> 6;
  const int wm = w >> 2;
  const int wn = w & 3;
  const int l15 = l & 15, lhi = l >> 4;
  const int lr = l >> 3;
  const int lc = ((l & 7) ^ lr) * 8;

  const ushort_t* Agb = A + (size_t)(tm * 256) * 2048;
  const ushort_t* Wgb = W + (size_t)(tn * 256) * 2048;

  GEMM_BODY()

#pragma unroll
  for (int qn = 0; qn < 2; ++qn)
#pragma unroll
    for (int fn = 0; fn < 2; ++fn) {
      const int e = tn * 256 + wn * 64 + qn * 32 + fn * 16 + l15;
      const float bvv = bias[e];
#pragma unroll
      for (int qm = 0; qm < 2; ++qm)
#pragma unroll
        for (int fm = 0; fm < 4; ++fm) {
          const int srow0 = tm * 256 + wm * 128 + qm * 64 + fm * 16 + lhi * 4;
          const f32x4 v4 = acc[qm * 4 + fm][qn * 2 + fn];
#pragma unroll
          for (int r = 0; r < 4; ++r)
            outp[(size_t)(srow0 + r) * D_ + e] = v4[r] + bvv;
        }
    }
}
#undef STAGE_A
#undef STAGE_B
#undef GEMM_BODY

// ---------------------------------------------------------------------------
// Causal flash attention — exact r10 version (double-buffered K/V LDS, 128-row
// blocks, ones-MFMA row-sum, swizzled P stride-64, (256,2), grid 512).
// r22 (C-write via LDS) regressed 16us -> scalar C stores kept.
// ---------------------------------------------------------------------------
__global__ __launch_bounds__(256, 2) void attn_kern(
    const ushort_t* __restrict__ Q,
    const ushort_t* __restrict__ K,
    const ushort_t* __restrict__ Vt,
    ushort_t* __restrict__ C)
{
  __shared__ ushort_t Ks[2][64 * 128];
  __shared__ ushort_t Vs[2][128 * 64];
  __shared__ ushort_t Pl[4][32 * 64];

  const int bid = blockIdx.x;
  const int i = bid >> 3;
  const int bh = (bid & 7) * 8 + (i >> 3);
  const int qp = i & 7;

  const ushort_t* Qg = Q + (size_t)bh * S_ * DK_;
  const ushort_t* Kg = K + (size_t)bh * S_ * DK_;
  const ushort_t* Vg = Vt + (size_t)bh * DK_ * S_;
  const int b = bh >> 4, h = bh & 15;

  const int t = threadIdx.x;
  const int l = t & 63;
  const int w = t >> 6;
  const int l15 = l & 15, lhi = l >> 4;

  const float cs = 0.08838834764831845f * 1.4426950408889634f;
  const float DEFER_RAW = 8.0f / cs;

  short8 ones;
#pragma unroll
  for (int j = 0; j < 8; ++j) ones[j] = (short)0x3F80;

  int koff[4], voff[4];
#pragma unroll
  for (int j = 0; j < 4; ++j) {
    const int krow = w * 16 + j * 4 + lhi;
    koff[j] = krow * DK_ + 8 * (l15 ^ ((j * 4 + lhi) & 7));
    const int vrow = (w * 4 + j) * 8 + (l >> 3);
    voff[j] = vrow * S_ + 8 * ((l & 7) ^ (l >> 3));
  }
  int kcol[4];
#pragma unroll
  for (int kt = 0; kt < 4; ++kt)
    kcol[kt] = ((kt * 64 + lhi * 16) ^ ((l15 & 7) << 4)) >> 1;
  int vcol[2];
#pragma unroll
  for (int hb = 0; hb < 2; ++hb)
    vcol[hb] = ((hb * 64 + lhi * 16) ^ ((l15 & 7) << 4)) >> 1;

#define STAGE_KV(pb, kvv) do {                                              \
    _Pragma("unroll")                                                       \
    for (int j = 0; j < 4; ++j) {                                           \
      gl_lds16(Kg + (size_t)(kvv) * DK_ + koff[j], Ks[pb] + (w * 4 + j) * 512); \
      gl_lds16(Vg + (size_t)(kvv) + voff[j],       Vs[pb] + (w * 4 + j) * 512); \
    }                                                                       \
  } while (0)

  for (int pass = 0; pass < 2; ++pass) {
    const int qb = pass ? (15 - qp) : qp;
    const int qrow0 = qb * 128 + w * 32;
    const int nkv = 2 * (qb + 1);

    short8 qa[2][4];
#pragma unroll
    for (int rf = 0; rf < 2; ++rf)
#pragma unroll
      for (int kt = 0; kt < 4; ++kt)
        qa[rf][kt] = *(const short8*)(Qg + (size_t)(qrow0 + rf * 16 + l15) * DK_ + kt * 32 + lhi * 8);

    f32x4 o[2][8] = {};
    f32x4 lsum[2] = {};
    float mrow[2][4];
#pragma unroll
    for (int rf = 0; rf < 2; ++rf)
#pragma unroll
      for (int r = 0; r < 4; ++r) mrow[rf][r] = -1e30f;

    STAGE_KV(0, 0);
    asm volatile("s_waitcnt vmcnt(0)" ::: "memory");
    __syncthreads();

    for (int kvt = 0; kvt < nkv; ++kvt) {
      const int kv = kvt * 64;
      const int p = kvt & 1;

      if (kvt + 1 < nkv) STAGE_KV(p ^ 1, kv + 64);

      f32x4 sf[2][4] = {};
      __builtin_amdgcn_s_setprio(1);
#pragma unroll
      for (int f = 0; f < 4; ++f) {
#pragma unroll
        for (int kt = 0; kt < 4; ++kt) {
          short8 kb = *(const short8*)(Ks[p] + (f * 16 + l15) * 128 + kcol[kt]);
          sf[0][f] = __builtin_amdgcn_mfma_f32_16x16x32_bf16(qa[0][kt], kb, sf[0][f], 0, 0, 0);
          sf[1][f] = __builtin_amdgcn_mfma_f32_16x16x32_bf16(qa[1][kt], kb, sf[1][f], 0, 0, 0);
        }
      }
      __builtin_amdgcn_s_setprio(0);

      float pmax[2][4];
#pragma unroll
      for (int rf = 0; rf < 2; ++rf)
#pragma unroll
        for (int r = 0; r < 4; ++r) pmax[rf][r] = -1e30f;
      const bool domask = (kv + 63 > qrow0);
      if (domask) {
#pragma unroll
        for (int f = 0; f < 4; ++f) {
          const int col = kv + f * 16 + l15;
#pragma unroll
          for (int rf = 0; rf < 2; ++rf)
#pragma unroll
            for (int r = 0; r < 4; ++r) {
              const int row = qrow0 + rf * 16 + lhi * 4 + r;
              if (col > row) sf[rf][f][r] = -1e30f;
              pmax[rf][r] = fmaxf(pmax[rf][r], sf[rf][f][r]);
            }
        }
      } else {
#pragma unroll
        for (int f = 0; f < 4; ++f)
#pragma unroll
          for (int rf = 0; rf < 2; ++rf)
#pragma unroll
            for (int r = 0; r < 4; ++r)
              pmax[rf][r] = fmaxf(pmax[rf][r], sf[rf][f][r]);
      }
#pragma unroll
      for (int d = 1; d < 16; d <<= 1)
#pragma unroll
        for (int rf = 0; rf < 2; ++rf)
#pragma unroll
          for (int r = 0; r < 4; ++r)
            pmax[rf][r] = fmaxf(pmax[rf][r], __shfl_xor(pmax[rf][r], d, 64));

      bool need = false;
#pragma unroll
      for (int rf = 0; rf < 2; ++rf)
#pragma unroll
        for (int r = 0; r < 4; ++r) need |= (pmax[rf][r] > mrow[rf][r] + DEFER_RAW);
      if (__any(need)) {
#pragma unroll
        for (int rf = 0; rf < 2; ++rf)
#pragma unroll
          for (int r = 0; r < 4; ++r) {
            const float mn = fmaxf(mrow[rf][r], pmax[rf][r]);
            const float alpha = __builtin_amdgcn_exp2f((mrow[rf][r] - mn) * cs);
            mrow[rf][r] = mn;
            lsum[rf][r] *= alpha;
#pragma unroll
            for (int n = 0; n < 8; ++n) o[rf][n][r] *= alpha;
          }
      }

      ushort_t* P = Pl[w];
#pragma unroll
      for (int f = 0; f < 4; ++f)
#pragma unroll
        for (int rf = 0; rf < 2; ++rf)
#pragma unroll
          for (int r = 0; r < 4; ++r) {
            const float pv = __builtin_amdgcn_exp2f((sf[rf][f][r] - mrow[rf][r]) * cs);
            const int prow = rf * 16 + lhi * 4 + r;
            P[prow * 64 + ((f * 16 + l15) ^ ((prow & 7) << 3))] = f2bf(pv);
          }

      asm volatile("s_waitcnt lgkmcnt(0)" ::: "memory");
      short8 pa[2][2];
#pragma unroll
      for (int rf = 0; rf < 2; ++rf)
#pragma unroll
        for (int ks = 0; ks < 2; ++ks) {
          const int prow = rf * 16 + l15;
          pa[rf][ks] = *(const short8*)(P + prow * 64 + ((ks * 32 + lhi * 8) ^ ((prow & 7) << 3)));
        }

      __builtin_amdgcn_s_setprio(1);
#pragma unroll
      for (int rf = 0; rf < 2; ++rf) {
        lsum[rf] = __builtin_amdgcn_mfma_f32_16x16x32_bf16(pa[rf][0], ones, lsum[rf], 0, 0, 0);
        lsum[rf] = __builtin_amdgcn_mfma_f32_16x16x32_bf16(pa[rf][1], ones, lsum[rf], 0, 0, 0);
      }
#pragma unroll
      for (int n = 0; n < 8; ++n) {
#pragma unroll
        for (int hb = 0; hb < 2; ++hb) {
          short8 vb = *(const short8*)(Vs[p] + (n * 16 + l15) * 64 + vcol[hb]);
          o[0][n] = __builtin_amdgcn_mfma_f32_16x16x32_bf16(pa[0][hb], vb, o[0][n], 0, 0, 0);
          o[1][n] = __builtin_amdgcn_mfma_f32_16x16x32_bf16(pa[1][hb], vb, o[1][n], 0, 0, 0);
        }
      }
      __builtin_amdgcn_s_setprio(0);

      asm volatile("s_waitcnt vmcnt(0)" ::: "memory");
      __syncthreads();
    }

#pragma unroll
    for (int rf = 0; rf < 2; ++rf) {
      float linv[4];
#pragma unroll
      for (int r = 0; r < 4; ++r) linv[r] = 1.0f / lsum[rf][r];
#pragma unroll
      for (int n = 0; n < 8; ++n) {
        const int dk = n * 16 + l15;
#pragma unroll
        for (int r = 0; r < 4; ++r) {
          const int srow = qrow0 + rf * 16 + lhi * 4 + r;
          C[(((size_t)b * S_ + srow) * H_ + h) * DK_ + dk] = f2bf(o[rf][n][r] * linv[r]);
        }
      }
    }
  }
#undef STAGE_KV
}

// ---------------------------------------------------------------------------
extern "C" void kernel_launch(void* const* d_in, const int* in_sizes, int n_in,
                              void* d_out, int out_size, void* d_ws, size_t ws_size,
                              hipStream_t stream) {
  const float* x  = (const float*)d_in[0];
  const float* Wq = (const float*)d_in[1];
  const float* bq = (const float*)d_in[2];
  const float* Wk = (const float*)d_in[3];
  const float* bk = (const float*)d_in[4];
  const float* Wv = (const float*)d_in[5];
  const float* bv = (const float*)d_in[6];
  const float* Wo = (const float*)d_in[7];
  const float* bo = (const float*)d_in[8];
  float* out = (float*)d_out;

  ushort_t* ws = (ushort_t*)d_ws;
  const size_t NE = (size_t)B_ * S_ * D_;
  const size_t NW = (size_t)D_ * D_;
  ushort_t* xb  = ws;
  ushort_t* Wqb = ws + NE;
  ushort_t* Wkb = Wqb + NW;
  ushort_t* Wvb = Wkb + NW;
  ushort_t* Wob = Wvb + NW;
  ushort_t* Qw  = Wob + NW;
  ushort_t* Kw  = Qw + NE;
  ushort_t* Vw  = Kw + NE;   // holds V^T (b,h,dk,s)
  ushort_t* Cw  = xb;

  const int XB = (int)(NE / 8 / 256);
  const int WB = (int)(NW / 8 / 256);
  cvt_all<<<dim3(XB + 4 * WB), dim3(256), 0, stream>>>(x, Wq, Wk, Wv, Wo, ws);

  gemmQKV<<<dim3(768), dim3(512), 0, stream>>>(xb, Wqb, Wkb, Wvb, bq, bk, bv, Qw, Kw, Vw);
  attn_kern<<<dim3(512), dim3(256), 0, stream>>>(Qw, Kw, Vw, Cw);
  gemmOut<<<dim3(256), dim3(512), 0, stream>>>(Cw, Wob, bo, out);
}